// Round 5
// baseline (335.512 us; speedup 1.0000x reference)
//
#include <hip/hip_runtime.h>
#include <hip/hip_bf16.h>

// QLayerQuantum: out[b][h] = sum_k cumprod(cos(x[b]))[k] * W[h][k] + bias[h]
// B=65536, NQ=32, H=1024. fp32 throughout (no fp32 MFMA on CDNA4; VALU has
// 1.55x headroom over the HBM write roofline, so fp32 vector math is free).

#define B_TOT 65536
#define NQ    32
#define H_TOT 1024
#define BM    32     // batch rows per block
#define BN    128    // hidden cols per block

// native clang vector for __builtin_nontemporal_store (HIP float4 is a class
// type the builtin rejects -- r3 compile error)
typedef float v4f __attribute__((ext_vector_type(4)));

__global__ __launch_bounds__(256) void qlayer_kernel(
    const float* __restrict__ x,   // [B][NQ]
    const float* __restrict__ W,   // [H][NQ]
    const float* __restrict__ bias,// [H]
    float* __restrict__ out)       // [B][H]
{
    __shared__ float zs[BM * NQ];        // 4 KB   z[row][k]
    __shared__ float wlds[NQ * BN];      // 16 KB  W_t[k][col]  (transposed for conflict-free reads)

    const int tid = threadIdx.x;                 // 0..255
    const int b0  = blockIdx.x * BM;
    const int h0  = blockIdx.y * BN;

    // ---- issue W tile global loads early (16 KB contiguous), hide under z-phase ----
    const float4* wg = reinterpret_cast<const float4*>(W + h0 * NQ); // 1024 float4
    float4 wv[4];
#pragma unroll
    for (int i = 0; i < 4; ++i) wv[i] = wg[i * 256 + tid];

    // ---- z-phase: product scan of cos(x) per row, 32-lane groups ----
    const int g = tid >> 5;      // group 0..7 (2 groups per wave)
    const int l = tid & 31;      // lane in group
#pragma unroll
    for (int p = 0; p < 4; ++p) {
        const int row = p * 8 + g;
        float v = __cosf(x[(b0 + row) * NQ + l]);
#pragma unroll
        for (int d = 1; d < 32; d <<= 1) {
            float o = __shfl_up(v, d, 32);
            if (l >= d) v *= o;
        }
        zs[row * NQ + l] = v;    // banks = l, conflict-free
    }

    // ---- stage W to LDS transposed: wlds[k][col] ----
    // (8-way write-side bank conflict here is a one-time ~tens-of-ns cost per
    //  block vs ~0.65us HBM budget -- measured-counter evidence required
    //  before spending a swizzle on it.)
#pragma unroll
    for (int i = 0; i < 4; ++i) {
        const int idx = i * 256 + tid;       // float4 index within tile
        const int h   = idx >> 3;            // (idx*4)/32  -> col 0..127
        const int k0  = (idx & 7) << 2;      // (idx*4)%32  -> k
        wlds[(k0 + 0) * BN + h] = wv[i].x;
        wlds[(k0 + 1) * BN + h] = wv[i].y;
        wlds[(k0 + 2) * BN + h] = wv[i].z;
        wlds[(k0 + 3) * BN + h] = wv[i].w;
    }
    __syncthreads();

    // ---- compute: thread owns 4 rows x 4 cols ----
    const int rg = tid >> 5;           // row group 0..7 -> rows rg*4..rg*4+3
    const int c4 = (tid & 31) << 2;    // col 0,4,...,124

    float acc[4][4];
#pragma unroll
    for (int r = 0; r < 4; ++r)
#pragma unroll
        for (int c = 0; c < 4; ++c) acc[r][c] = 0.f;

#pragma unroll
    for (int k0 = 0; k0 < NQ; k0 += 4) {
        // 4 b128 reads: cols c4..c4+3 at fixed k (stride BN=128 floats)
        const float4 w0 = *reinterpret_cast<const float4*>(&wlds[(k0 + 0) * BN + c4]);
        const float4 w1 = *reinterpret_cast<const float4*>(&wlds[(k0 + 1) * BN + c4]);
        const float4 w2 = *reinterpret_cast<const float4*>(&wlds[(k0 + 2) * BN + c4]);
        const float4 w3 = *reinterpret_cast<const float4*>(&wlds[(k0 + 3) * BN + c4]);
#pragma unroll
        for (int r = 0; r < 4; ++r) {
            // half-wave broadcast read (all 32 lanes same address) - free
            const float4 z4 = *reinterpret_cast<const float4*>(&zs[(rg * 4 + r) * NQ + k0]);
            acc[r][0] += z4.x * w0.x + z4.y * w1.x + z4.z * w2.x + z4.w * w3.x;
            acc[r][1] += z4.x * w0.y + z4.y * w1.y + z4.z * w2.y + z4.w * w3.y;
            acc[r][2] += z4.x * w0.z + z4.y * w1.z + z4.z * w2.z + z4.w * w3.z;
            acc[r][3] += z4.x * w0.w + z4.y * w1.w + z4.z * w2.w + z4.w * w3.w;
        }
    }

    // ---- epilogue: bias + streaming stores ----
    const float4 bv = *reinterpret_cast<const float4*>(&bias[h0 + c4]);
#pragma unroll
    for (int r = 0; r < 4; ++r) {
        v4f o;
        o.x = acc[r][0] + bv.x;
        o.y = acc[r][1] + bv.y;
        o.z = acc[r][2] + bv.z;
        o.w = acc[r][3] + bv.w;
        v4f* dst = reinterpret_cast<v4f*>(
            &out[(size_t)(b0 + rg * 4 + r) * H_TOT + h0 + c4]);
        __builtin_nontemporal_store(o, dst);   // 256 MB streaming write, never re-read
    }
}

extern "C" void kernel_launch(void* const* d_in, const int* in_sizes, int n_in,
                              void* d_out, int out_size, void* d_ws, size_t ws_size,
                              hipStream_t stream) {
    const float* x = (const float*)d_in[0];
    const float* W = (const float*)d_in[1];
    const float* b = (const float*)d_in[2];
    float* out = (float*)d_out;

    dim3 grid(B_TOT / BM, H_TOT / BN);   // 2048 x 8
    dim3 block(256);
    qlayer_kernel<<<grid, block, 0, stream>>>(x, W, b, out);
}

// Round 11
// 302.286 us; speedup vs baseline: 1.1099x; 1.1099x over previous
//
#include <hip/hip_runtime.h>
#include <hip/hip_bf16.h>

// QLayerQuantum: out[b][h] = sum_k cumprod(cos(x[b]))[k] * W[h][k] + bias[h]
// B=65536, NQ=32, H=1024.
//
// r5 post-mortem: fused LDS-tiled version hit 335us vs 42us HBM-write floor.
// Identified LDS pipe as co-limiter (64 ds_read_b128 per wave per block,
// LDS shared across 4 SIMDs/CU). This version has ZERO LDS in the GEMM:
//   k1: z = cumprod(cos(x)) -> ws (8 MB fp32)
//   k2: W cols in VGPRs (2 cols x 32 k = 64 regs/thread, loaded once),
//       z rows via wave-uniform loads (-> s_load / broadcast VMEM, K$ pipe),
//       64 FMA + one nontemporal float2 store per row. No __syncthreads.

#define B_TOT 65536
#define NQ    32
#define H_TOT 1024
#define ROWS_PER_BLK 64
#define COLS_PER_BLK 512   // 256 threads * 2 cols

typedef float v2f __attribute__((ext_vector_type(2)));

__global__ __launch_bounds__(256) void zscan_kernel(
    const float* __restrict__ x,   // [B][NQ]
    float* __restrict__ z)         // [B][NQ] out
{
    const int g = threadIdx.x >> 5;      // 8 row-groups per block
    const int l = threadIdx.x & 31;
    const int row = blockIdx.x * 8 + g;
    float v = __cosf(x[row * NQ + l]);
#pragma unroll
    for (int d = 1; d < 32; d <<= 1) {   // inclusive product scan over 32 lanes
        float o = __shfl_up(v, d, 32);
        if (l >= d) v *= o;
    }
    z[row * NQ + l] = v;
}

__global__ __launch_bounds__(256) void gemm_kernel(
    const float* __restrict__ z,    // [B][NQ]
    const float* __restrict__ W,    // [H][NQ]
    const float* __restrict__ bias, // [H]
    float* __restrict__ out)        // [B][H]
{
    const int tid = threadIdx.x;
    const int r0  = blockIdx.x * ROWS_PER_BLK;
    const int c0  = blockIdx.y * COLS_PER_BLK + tid * 2;

    // ---- W columns c0, c0+1 into registers (one-time, 64 KB/block from L2) ----
    float w0[NQ], w1[NQ];
    const float4* wg0 = reinterpret_cast<const float4*>(W + (size_t)c0 * NQ);
    const float4* wg1 = reinterpret_cast<const float4*>(W + (size_t)(c0 + 1) * NQ);
#pragma unroll
    for (int i = 0; i < 8; ++i) {
        float4 a = wg0[i];
        w0[4*i+0] = a.x; w0[4*i+1] = a.y; w0[4*i+2] = a.z; w0[4*i+3] = a.w;
        float4 b = wg1[i];
        w1[4*i+0] = b.x; w1[4*i+1] = b.y; w1[4*i+2] = b.z; w1[4*i+3] = b.w;
    }
    const float b0 = bias[c0];
    const float b1 = bias[c0 + 1];

    // z rows for this block: addresses are tid-independent -> wave-uniform
    const float4* zp = reinterpret_cast<const float4*>(z + (size_t)r0 * NQ);
    float* op = out + (size_t)r0 * H_TOT + c0;

#pragma unroll 1
    for (int r = 0; r < ROWS_PER_BLK; ++r) {
        float zk[NQ];                       // statically indexed -> registers
#pragma unroll
        for (int i = 0; i < 8; ++i) {
            float4 t = zp[r * 8 + i];       // uniform address: s_load / bcast
            zk[4*i+0] = t.x; zk[4*i+1] = t.y; zk[4*i+2] = t.z; zk[4*i+3] = t.w;
        }
        float a0 = b0, a1 = b1;
#pragma unroll
        for (int k = 0; k < NQ; ++k) {
            a0 += zk[k] * w0[k];
            a1 += zk[k] * w1[k];
        }
        v2f o; o.x = a0; o.y = a1;
        __builtin_nontemporal_store(o,
            reinterpret_cast<v2f*>(op + (size_t)r * H_TOT));  // 512B/wave contiguous
    }
}

extern "C" void kernel_launch(void* const* d_in, const int* in_sizes, int n_in,
                              void* d_out, int out_size, void* d_ws, size_t ws_size,
                              hipStream_t stream) {
    const float* x = (const float*)d_in[0];
    const float* W = (const float*)d_in[1];
    const float* b = (const float*)d_in[2];
    float* out = (float*)d_out;
    float* z   = (float*)d_ws;           // 8 MB of the 1 GiB workspace

    zscan_kernel<<<dim3(B_TOT / 8), dim3(256), 0, stream>>>(x, z);
    gemm_kernel<<<dim3(B_TOT / ROWS_PER_BLK, H_TOT / COLS_PER_BLK),
                  dim3(256), 0, stream>>>(z, W, b, out);
}